// Round 2
// baseline (293.313 us; speedup 1.0000x reference)
//
#include <hip/hip_runtime.h>

// VectorQuantizer on MI355X (gfx950)
// z:   [B=128, C=128, H=32, W=32] f32   -> pixel n = b*1024 + hw, channel stride 1024
// emb: [K=256, C=128] f32
// out: [quantized_st 16777216][indices 131072][commit 1][codebook 1]  (f32)
//
// Distance argmin mimics the reference's f32 rounding:
//   d_k = fl( fl(zz - 2*s_k) + ee_k ),  zz = sequential f32 sum of fl(z_c*z_c)

#define VQ_C   128
#define VQ_K   256
#define VQ_HW  1024
#define VQ_B   128
#define VQ_NPIX (VQ_B * VQ_HW)          // 131072
#define VQ_QELEMS 16777216              // B*C*H*W
#define VQ_NBLOCKS 512                  // NPIX / 256

// ws layout (floats): [0..255] ee[k]; [256..767] per-block loss partials
__global__ void vq_prep(const float* __restrict__ emb, float* __restrict__ ws) {
    int k = threadIdx.x;               // 256 threads
    float s = 0.0f;
#pragma unroll
    for (int c = 0; c < VQ_C; ++c) {
        float e = emb[k * VQ_C + c];
        s = __fadd_rn(s, __fmul_rn(e, e));
    }
    ws[k] = s;
}

__global__ __launch_bounds__(256, 2) void vq_main(const float* __restrict__ z,
                                                  const float* __restrict__ emb,
                                                  const float* __restrict__ ee,
                                                  float* __restrict__ partials,
                                                  float* __restrict__ out) {
    const int n  = blockIdx.x * 256 + threadIdx.x;   // pixel id, exact grid
    const int b  = n >> 10;
    const int hw = n & 1023;
    const float* __restrict__ zp = z + (size_t)b * (VQ_C * VQ_HW) + hw;

    // Load my z row (coalesced per-c: 64 lanes contiguous in hw)
    float zr[VQ_C];
#pragma unroll
    for (int c = 0; c < VQ_C; ++c) zr[c] = zp[c * VQ_HW];

    // zz: sequential mul-then-add in f32 (mimic reference sum order)
    float zz = 0.0f;
#pragma unroll
    for (int c = 0; c < VQ_C; ++c) zz = __fadd_rn(zz, __fmul_rn(zr[c], zr[c]));

    float dmin = INFINITY;
    int   imin = 0;

#pragma unroll 1
    for (int k0 = 0; k0 < VQ_K; k0 += 8) {
        float s[8];
        // kk-outer, c-inner: emb rows contiguous -> wave-uniform scalar loads;
        // both loops fully unrolled -> 1024 independent-chain FMAs (8-way ILP).
#pragma unroll
        for (int kk = 0; kk < 8; ++kk) {
            const float* __restrict__ er = emb + (k0 + kk) * VQ_C;
            float acc = 0.0f;
#pragma unroll
            for (int c = 0; c < VQ_C; ++c) acc = fmaf(zr[c], er[c], acc);
            s[kk] = acc;
        }
        // d_k with reference rounding; strict < keeps first-occurrence argmin
#pragma unroll
        for (int kk = 0; kk < 8; ++kk) {
            float d = __fadd_rn(__fsub_rn(zz, __fadd_rn(s[kk], s[kk])), ee[k0 + kk]);
            if (d < dmin) { dmin = d; imin = k0 + kk; }
        }
    }

    // Gather codebook row, write quantized_st = fl(z + fl(q - z)), accumulate loss
    const float* __restrict__ eq = emb + imin * VQ_C;
    float* __restrict__ op = out + (size_t)b * (VQ_C * VQ_HW) + hw;
    float lsum = 0.0f;
#pragma unroll
    for (int c = 0; c < VQ_C; ++c) {
        float q    = eq[c];
        float diff = __fsub_rn(q, zr[c]);
        op[c * VQ_HW] = __fadd_rn(zr[c], diff);
        lsum = fmaf(diff, diff, lsum);
    }
    out[VQ_QELEMS + n] = (float)imin;

    // Deterministic block reduction -> per-block partial
    __shared__ float red[4];
    const int lane = threadIdx.x & 63;
    const int wid  = threadIdx.x >> 6;
#pragma unroll
    for (int off = 32; off > 0; off >>= 1) lsum += __shfl_down(lsum, off, 64);
    if (lane == 0) red[wid] = lsum;
    __syncthreads();
    if (threadIdx.x == 0)
        partials[blockIdx.x] = (red[0] + red[1]) + (red[2] + red[3]);
}

__global__ void vq_fin(const float* __restrict__ partials, float* __restrict__ out) {
    double acc = 0.0;
    for (int i = 0; i < VQ_NBLOCKS; ++i) acc += (double)partials[i];
    float m = (float)(acc * (1.0 / (double)VQ_QELEMS));
    out[VQ_QELEMS + VQ_NPIX + 0] = 0.25f * m;  // commitment
    out[VQ_QELEMS + VQ_NPIX + 1] = m;          // codebook
}

extern "C" void kernel_launch(void* const* d_in, const int* in_sizes, int n_in,
                              void* d_out, int out_size, void* d_ws, size_t ws_size,
                              hipStream_t stream) {
    const float* z   = (const float*)d_in[0];
    const float* emb = (const float*)d_in[1];
    float* out = (float*)d_out;
    float* ws  = (float*)d_ws;            // [0..255]=ee, [256..767]=partials

    vq_prep<<<1, 256, 0, stream>>>(emb, ws);
    vq_main<<<VQ_NBLOCKS, 256, 0, stream>>>(z, emb, ws, ws + 256, out);
    vq_fin<<<1, 1, 0, stream>>>(ws + 256, out);
}